// Round 8
// baseline (348.309 us; speedup 1.0000x reference)
//
#include <hip/hip_runtime.h>

typedef unsigned short ushort_t;
typedef __attribute__((ext_vector_type(8))) short short8;
typedef __attribute__((ext_vector_type(4))) float f32x4;

#define EMBED 1024
#define NHEADS 16
#define HDIM 64
#define SEQ 2048
#define BATCH 2
#define BS (BATCH*SEQ)              // 4096
#define QSCALE 0.045084234f         // log2(e)/sqrt(1024): fold softmax scale + exp2 conversion into Q

// round-to-nearest-even fp32 -> bf16
static __device__ __forceinline__ ushort_t f2b(float x) {
    union { float f; unsigned u; } v; v.f = x;
    unsigned r = v.u + 0x7FFFu + ((v.u >> 16) & 1u);
    return (ushort_t)(r >> 16);
}

// ---------------------------------------------------------------------------
// Transpose-cast: src fp32 [K][N] row-major  ->  dst bf16 [N][K] row-major.
// ---------------------------------------------------------------------------
__global__ __launch_bounds__(256) void tcast_kernel(
    const float* __restrict__ src, ushort_t* __restrict__ dst,
    int N, int nshift, int K, int total4)
{
    int t = blockIdx.x * 256 + threadIdx.x;
    if (t >= total4) return;
    int n = t & (N - 1);
    int k0 = (t >> nshift) << 2;
    ushort4 o;
    o.x = f2b(src[(size_t)(k0 + 0) * N + n]);
    o.y = f2b(src[(size_t)(k0 + 1) * N + n]);
    o.z = f2b(src[(size_t)(k0 + 2) * N + n]);
    o.w = f2b(src[(size_t)(k0 + 3) * N + n]);
    *reinterpret_cast<ushort4*>(dst + (size_t)n * K + k0) = o;
}

// ---------------------------------------------------------------------------
// MFMA GEMM (unchanged from validated Round-7 version).
// ---------------------------------------------------------------------------
template<int MODE>
__global__ __launch_bounds__(256) void mfma_gemm(
    const float* __restrict__ Af, const ushort_t* __restrict__ Ab,
    const ushort_t* __restrict__ Bt,
    const float* __restrict__ bias0, const float* __restrict__ bias1,
    float* __restrict__ Of, ushort_t* __restrict__ Ob, ushort_t* __restrict__ Ovt)
{
    __shared__ ushort_t As[128 * 32];
    __shared__ ushort_t Bs[128 * 32];

    const int tid = threadIdx.x;
    const int lane = tid & 63;
    const int w = tid >> 6;
    const int g = lane >> 4;        // 0..3
    const int c = lane & 15;        // 0..15
    const int wy = w >> 1, wx = w & 1;
    const int rowBase = blockIdx.y * 128;
    const int colBase = blockIdx.x * 128;

    f32x4 acc[4][4];
    #pragma unroll
    for (int i = 0; i < 4; ++i)
        #pragma unroll
        for (int j = 0; j < 4; ++j)
            acc[i][j] = (f32x4){0.f, 0.f, 0.f, 0.f};

    for (int kk = 0; kk < 1024; kk += 32) {
        __syncthreads();
        if (MODE != 2) {
            #pragma unroll
            for (int u = 0; u < 2; ++u) {
                const int o = tid * 32 + u * 16;
                const int row = o >> 6, kb = o & 63;
                const float* s = Af + (size_t)(rowBase + row) * 1024 + kk + (kb >> 1);
                float4 f0 = *reinterpret_cast<const float4*>(s);
                float4 f1 = *reinterpret_cast<const float4*>(s + 4);
                short8 h;
                h[0] = (short)f2b(f0.x); h[1] = (short)f2b(f0.y);
                h[2] = (short)f2b(f0.z); h[3] = (short)f2b(f0.w);
                h[4] = (short)f2b(f1.x); h[5] = (short)f2b(f1.y);
                h[6] = (short)f2b(f1.z); h[7] = (short)f2b(f1.w);
                *reinterpret_cast<short8*>((char*)As + (o ^ ((row & 3) << 4))) = h;
            }
        } else {
            #pragma unroll
            for (int u = 0; u < 2; ++u) {
                const int o = u * 4096 + tid * 16;
                const int row = o >> 6, kb = o & 63;
                const ushort_t* s = Ab + (size_t)(rowBase + row) * 1024 + kk + (kb >> 1);
                *reinterpret_cast<short8*>((char*)As + (o ^ ((row & 3) << 4))) =
                    *reinterpret_cast<const short8*>(s);
            }
        }
        #pragma unroll
        for (int u = 0; u < 2; ++u) {
            const int o = u * 4096 + tid * 16;
            const int row = o >> 6, kb = o & 63;
            const ushort_t* s = Bt + (size_t)(colBase + row) * 1024 + kk + (kb >> 1);
            *reinterpret_cast<short8*>((char*)Bs + (o ^ ((row & 3) << 4))) =
                *reinterpret_cast<const short8*>(s);
        }
        __syncthreads();

        short8 af[4], bf[4];
        #pragma unroll
        for (int mt = 0; mt < 4; ++mt) {
            const int row = wy * 64 + mt * 16 + c;
            af[mt] = *reinterpret_cast<const short8*>(
                (const char*)As + row * 64 + ((g * 16) ^ ((row & 3) << 4)));
        }
        #pragma unroll
        for (int nt = 0; nt < 4; ++nt) {
            const int row = wx * 64 + nt * 16 + c;
            bf[nt] = *reinterpret_cast<const short8*>(
                (const char*)Bs + row * 64 + ((g * 16) ^ ((row & 3) << 4)));
        }
        #pragma unroll
        for (int mt = 0; mt < 4; ++mt)
            #pragma unroll
            for (int nt = 0; nt < 4; ++nt)
                acc[mt][nt] = __builtin_amdgcn_mfma_f32_16x16x32_bf16(
                    af[mt], bf[nt], acc[mt][nt], 0, 0, 0);
    }

    #pragma unroll
    for (int nt = 0; nt < 4; ++nt) {
        const int colAbs = colBase + wx * 64 + nt * 16 + c;
        float bv0;
        if (MODE == 1) bv0 = (colAbs < 64) ? bias0[colAbs] : bias1[colAbs - 64];
        else           bv0 = bias0[colAbs];
        #pragma unroll
        for (int mt = 0; mt < 4; ++mt) {
            const int rowA = rowBase + wy * 64 + mt * 16 + g * 4;
            #pragma unroll
            for (int r = 0; r < 4; ++r) {
                const float v = acc[mt][nt][r] + bv0;
                const int row = rowA + r;
                if (MODE == 0) {
                    Ob[(size_t)row * 1024 + colAbs] = f2b(v * QSCALE);
                } else if (MODE == 2) {
                    Of[(size_t)row * 1024 + colAbs] = v;
                } else {
                    if (colAbs < 64)
                        Ob[(size_t)row * 64 + colAbs] = f2b(v);
                    else
                        Ovt[((size_t)(row >> 11) * 64 + (colAbs - 64)) * 2048 + (row & 2047)] = f2b(v);
                }
            }
        }
    }
}

// ---------------------------------------------------------------------------
// MFMA MQA flash attention, software-pipelined.
// Wave-private P tile; S^T = K.Q^T; out^T = V^T.P^T; no barriers, no fences.
// K register-double-buffered (cur/nxt); V issued at iteration top, consumed
// after softmax (counted-vmcnt overlap is compiler-derived from dataflow).
// Defer-max (THR=8 in exp2 domain) skips O-rescale on most tiles.
// ---------------------------------------------------------------------------
#define PSWZ(row, kbyte) ((row) * 128 + ((kbyte) ^ (((row) & 7) << 4)))

static __device__ __forceinline__ void attn_body(
    int kt, const ushort_t* kbase, const ushort_t* vbase,
    short8 (&cur)[4][2], short8 (&nxt)[4][2],
    const short8 (&bq)[2], f32x4 (&oacc)[4],
    float& m_run, float& l_run, char* pl, int c, int g)
{
    // ---- issue V(kt) then K(kt+1) loads (clamped); consumed much later ----
    short8 av[4][2];
    const int ktn = (kt + 1 < SEQ / 64) ? kt + 1 : (SEQ / 64 - 1);
    #pragma unroll
    for (int mt = 0; mt < 4; ++mt) {
        av[mt][0] = *reinterpret_cast<const short8*>(vbase + (size_t)(mt * 16) * 2048 + kt * 64);
        av[mt][1] = *reinterpret_cast<const short8*>(vbase + (size_t)(mt * 16) * 2048 + kt * 64 + 32);
        nxt[mt][0] = *reinterpret_cast<const short8*>(kbase + ((size_t)ktn * 64 + mt * 16) * 64);
        nxt[mt][1] = *reinterpret_cast<const short8*>(kbase + ((size_t)ktn * 64 + mt * 16) * 64 + 32);
    }

    // ---- S^T tile from resident K (cur): D[key=mt*16+g*4+r][qrow=c] ----
    f32x4 sacc[4];
    #pragma unroll
    for (int mt = 0; mt < 4; ++mt) {
        sacc[mt] = (f32x4){0.f, 0.f, 0.f, 0.f};
        sacc[mt] = __builtin_amdgcn_mfma_f32_16x16x32_bf16(cur[mt][0], bq[0], sacc[mt], 0, 0, 0);
        sacc[mt] = __builtin_amdgcn_mfma_f32_16x16x32_bf16(cur[mt][1], bq[1], sacc[mt], 0, 0, 0);
    }

    // ---- online softmax (row owned by lane; 4 lanes share row via shfl) ----
    float pmax = sacc[0][0];
    #pragma unroll
    for (int mt = 0; mt < 4; ++mt)
        #pragma unroll
        for (int r = 0; r < 4; ++r)
            pmax = fmaxf(pmax, sacc[mt][r]);
    pmax = fmaxf(pmax, __shfl_xor(pmax, 16));
    pmax = fmaxf(pmax, __shfl_xor(pmax, 32));

    if (!__all(pmax - m_run <= 8.0f)) {         // rare rescale path (T13)
        const float mn = fmaxf(m_run, pmax);
        const float al = exp2f(m_run - mn);
        m_run = mn;
        l_run *= al;
        #pragma unroll
        for (int mt = 0; mt < 4; ++mt)
            #pragma unroll
            for (int r = 0; r < 4; ++r)
                oacc[mt][r] *= al;
    }

    float rs = 0.f;
    #pragma unroll
    for (int mt = 0; mt < 4; ++mt) {
        const float p0 = exp2f(sacc[mt][0] - m_run);
        const float p1 = exp2f(sacc[mt][1] - m_run);
        const float p2 = exp2f(sacc[mt][2] - m_run);
        const float p3 = exp2f(sacc[mt][3] - m_run);
        rs += (p0 + p1) + (p2 + p3);
        uint2 pk;
        asm("v_cvt_pk_bf16_f32 %0, %1, %2" : "=v"(pk.x) : "v"(p0), "v"(p1));
        asm("v_cvt_pk_bf16_f32 %0, %1, %2" : "=v"(pk.y) : "v"(p2), "v"(p3));
        *reinterpret_cast<uint2*>(pl + PSWZ(c, mt * 32 + g * 8)) = pk;
    }
    rs += __shfl_xor(rs, 16);
    rs += __shfl_xor(rs, 32);
    l_run += rs;

    // ---- out^T += V^T . P^T (P read back transposed per-wave) ----
    #pragma unroll
    for (int ks = 0; ks < 2; ++ks) {
        short8 pf = *reinterpret_cast<const short8*>(pl + PSWZ(c, ks * 64 + g * 16));
        #pragma unroll
        for (int mt = 0; mt < 4; ++mt)
            oacc[mt] = __builtin_amdgcn_mfma_f32_16x16x32_bf16(av[mt][ks], pf, oacc[mt], 0, 0, 0);
    }
}

__global__ __launch_bounds__(256, 3) void attn_mfma_kernel(
    const ushort_t* __restrict__ q,   // [4096][1024] bf16, pre-scaled
    const ushort_t* __restrict__ kb,  // [4096][64]   bf16
    const ushort_t* __restrict__ vt,  // [2][64][2048] bf16
    ushort_t* __restrict__ aout)      // [4096][1024] bf16
{
    __shared__ char P_lds[4 * 2048];  // per-wave 16 rows x 64 keys bf16

    const int tid = threadIdx.x;
    const int lane = tid & 63;
    const int w = tid >> 6;
    const int g = lane >> 4;          // 0..3
    const int c = lane & 15;          // q-row within wave
    const int bid = blockIdx.x;
    const int qt = bid & 31;
    const int h = (bid >> 5) & 15;
    const int b = bid >> 9;
    const int q0 = qt * 64;

    char* pl = P_lds + w * 2048;

    short8 bq[2];
    {
        const size_t qrow = (size_t)(b * SEQ + q0 + w * 16 + c) * 1024 + h * 64;
        bq[0] = *reinterpret_cast<const short8*>(q + qrow + g * 8);
        bq[1] = *reinterpret_cast<const short8*>(q + qrow + 32 + g * 8);
    }

    const ushort_t* kbase = kb + ((size_t)b * SEQ + c) * 64 + g * 8;
    const ushort_t* vbase = vt + ((size_t)b * 64 + c) * 2048 + g * 8;

    f32x4 oacc[4];
    #pragma unroll
    for (int i = 0; i < 4; ++i) oacc[i] = (f32x4){0.f, 0.f, 0.f, 0.f};
    float m_run = -1e30f, l_run = 0.f;

    short8 akA[4][2], akB[4][2];
    #pragma unroll
    for (int mt = 0; mt < 4; ++mt) {          // prologue: K tile 0
        akA[mt][0] = *reinterpret_cast<const short8*>(kbase + (size_t)(mt * 16) * 64);
        akA[mt][1] = *reinterpret_cast<const short8*>(kbase + (size_t)(mt * 16) * 64 + 32);
    }

    for (int kt = 0; kt < SEQ / 64; kt += 2) {
        attn_body(kt,     kbase, vbase, akA, akB, bq, oacc, m_run, l_run, pl, c, g);
        attn_body(kt + 1, kbase, vbase, akB, akA, bq, oacc, m_run, l_run, pl, c, g);
    }

    // ---- epilogue: out^T -> LDS transpose -> coalesced bf16 store ----
    const float linv = 1.0f / l_run;
    #pragma unroll
    for (int mt = 0; mt < 4; ++mt) {
        uint2 ok;
        ok.x = (unsigned)f2b(oacc[mt][0] * linv) | ((unsigned)f2b(oacc[mt][1] * linv) << 16);
        ok.y = (unsigned)f2b(oacc[mt][2] * linv) | ((unsigned)f2b(oacc[mt][3] * linv) << 16);
        *reinterpret_cast<uint2*>(pl + PSWZ(c, mt * 32 + g * 8)) = ok;
    }
    {
        const int qr = lane >> 2, ch = lane & 3;
        uint4 d0 = *reinterpret_cast<const uint4*>(pl + PSWZ(qr, ch * 32));
        uint4 d1 = *reinterpret_cast<const uint4*>(pl + PSWZ(qr, ch * 32 + 16));
        ushort_t* dst = aout + (size_t)(b * SEQ + q0 + w * 16 + qr) * 1024 + h * 64 + ch * 16;
        *reinterpret_cast<uint4*>(dst) = d0;
        *reinterpret_cast<uint4*>(dst + 8) = d1;
    }
}

// ---------------------------------------------------------------------------
extern "C" void kernel_launch(void* const* d_in, const int* in_sizes, int n_in,
                              void* d_out, int out_size, void* d_ws, size_t ws_size,
                              hipStream_t stream) {
    const float* x  = (const float*)d_in[0];
    const float* wq = (const float*)d_in[1];
    const float* bq = (const float*)d_in[2];
    const float* wk = (const float*)d_in[3];
    const float* bk = (const float*)d_in[4];
    const float* wv = (const float*)d_in[5];
    const float* bv = (const float*)d_in[6];
    const float* wo = (const float*)d_in[7];
    const float* bo = (const float*)d_in[8];
    float* out = (float*)d_out;

    // ws layout (bf16 elements). Total 13.25 MB.
    ushort_t* ws    = (ushort_t*)d_ws;
    ushort_t* wq_t  = ws;                        // [1024][1024]
    ushort_t* wo_t  = wq_t + 1024 * 1024;        // [1024][1024]
    ushort_t* wkv_t = wo_t + 1024 * 1024;        // [128][1024]
    ushort_t* kbuf  = wkv_t + 128 * 1024;        // [4096][64]
    ushort_t* vtb   = kbuf + (size_t)BS * 64;    // [2][64][2048]
    ushort_t* abuf  = vtb + (size_t)BS * 64;     // [4096][1024]
    ushort_t* qbuf  = (ushort_t*)d_out;          // [4096][1024] staged in d_out

    tcast_kernel<<<1024, 256, 0, stream>>>(wq, wq_t, 1024, 10, 1024, 1024 * 256);
    tcast_kernel<<<1024, 256, 0, stream>>>(wo, wo_t, 1024, 10, 1024, 1024 * 256);
    tcast_kernel<<<64, 256, 0, stream>>>(wk, wkv_t,             64, 6, 1024, 64 * 256);
    tcast_kernel<<<64, 256, 0, stream>>>(wv, wkv_t + 64 * 1024, 64, 6, 1024, 64 * 256);

    mfma_gemm<0><<<dim3(8, 32), 256, 0, stream>>>(x, nullptr, wq_t, bq, nullptr,
                                                  nullptr, qbuf, nullptr);
    mfma_gemm<1><<<dim3(1, 32), 256, 0, stream>>>(x, nullptr, wkv_t, bk, bv,
                                                  nullptr, kbuf, vtb);
    attn_mfma_kernel<<<BATCH * NHEADS * (SEQ / 64), 256, 0, stream>>>(qbuf, kbuf, vtb, abuf);
    mfma_gemm<2><<<dim3(8, 32), 256, 0, stream>>>(nullptr, abuf, wo_t, bo, nullptr,
                                                  out, nullptr, nullptr);
}